// Round 1
// baseline (2774.406 us; speedup 1.0000x reference)
//
#include <hip/hip_runtime.h>
#include <stdint.h>

typedef unsigned short u16;
typedef unsigned int u32;
typedef __attribute__((ext_vector_type(4))) float f32x4;
typedef __attribute__((ext_vector_type(8))) short bf16x8;

#define MROWS 16384
#define NP    2560   // padded N / K for 2500-dims
#define K1P   2688   // padded K for 2675 (train_feat / W1_self)

// ---------------- helpers ----------------

__device__ __forceinline__ u16 f2bf(float f) {
    u32 u = __float_as_uint(f);
    u32 r = (u + 0x7fffu + ((u >> 16) & 1u)) >> 16;   // round-to-nearest-even
    return (u16)r;
}

__device__ __forceinline__ void async_ld16(const void* g, void* l) {
    __builtin_amdgcn_global_load_lds((const __attribute__((address_space(1))) u32*)g,
                                     (__attribute__((address_space(3))) u32*)l,
                                     16, 0, 0);
}

// ---------------- prep kernels ----------------

// fp32 [R,C] -> bf16 [gridDim.x, Cp], zero-padded. grid.x = Rp, block = 256.
__global__ void cvt_pad(const float* __restrict__ src, u16* __restrict__ dst,
                        int R, int C, int Cp) {
    const int r = blockIdx.x;
    u16* drow = dst + (size_t)r * Cp;
    if (r < R) {
        const float* srow = src + (size_t)r * C;
        for (int c = threadIdx.x; c < Cp; c += blockDim.x)
            drow[c] = (c < C) ? f2bf(srow[c]) : (u16)0;
    } else {
        for (int c = threadIdx.x; c < Cp; c += blockDim.x) drow[c] = 0;
    }
}

// fp32 vec [n] -> fp32 [np] zero-padded
__global__ void pad_vec(const float* __restrict__ src, float* __restrict__ dst,
                        int n, int np) {
    int i = blockIdx.x * blockDim.x + threadIdx.x;
    if (i < np) dst[i] = (i < n) ? src[i] : 0.f;
}

// gene_feat [2500,2500] fp32 -> dst [NP,NP] bf16, dst[n][k] = src[k][n], padded 0
__global__ void transpose_cvt(const float* __restrict__ src, u16* __restrict__ dst) {
    __shared__ float t[64][65];
    const int n0 = blockIdx.x * 64;
    const int k0 = blockIdx.y * 64;
    const int tx = threadIdx.x, ty = threadIdx.y;  // (64,4)
    for (int i = ty; i < 64; i += 4) {
        int k = k0 + i, n = n0 + tx;
        t[i][tx] = (k < 2500 && n < 2500) ? src[(size_t)k * 2500 + n] : 0.f;
    }
    __syncthreads();
    for (int i = ty; i < 64; i += 4)
        dst[(size_t)(n0 + i) * NP + k0 + tx] = f2bf(t[tx][i]);
}

__global__ void build_counts(const int* __restrict__ esrc, const int* __restrict__ edst,
                             int E, float* __restrict__ acnt) {
    int i = blockIdx.x * blockDim.x + threadIdx.x;
    if (i < E) atomicAdd(&acnt[(size_t)edst[i] * NP + esrc[i]], 1.0f);
}

// one wave per row: rdeg[row] = 1/max(rowsum,1)
__global__ void row_rdeg(const float* __restrict__ acnt, float* __restrict__ rdeg) {
    const int row = blockIdx.x;
    const float4* p = (const float4*)(acnt + (size_t)row * NP);
    float s = 0.f;
    for (int i = threadIdx.x; i < NP / 4; i += 64) {
        float4 v = p[i];
        s += v.x + v.y + v.z + v.w;
    }
    #pragma unroll
    for (int off = 32; off > 0; off >>= 1) s += __shfl_down(s, off, 64);
    if (threadIdx.x == 0) rdeg[row] = 1.f / fmaxf(s, 1.f);
}

// ---------------- main MFMA GEMM ----------------
// C[M,N](bf16) = epilogue( A1[M,K1] @ B1[N,K1]^T (+ A2[M,K2] @ B2[N,K2]^T) )
// BIAS_RELU: epilogue = relu(acc + bias[col]); else: acc * rdeg[row]
// All dims padded: M%128==0, N%128==0, K%64==0. All matrices bf16 row-major.
template<bool PAIR2, bool BIAS_RELU>
__global__ __launch_bounds__(256) void gemm_bt(
    const u16* __restrict__ A1, const u16* __restrict__ B1, int K1,
    const u16* __restrict__ A2, const u16* __restrict__ B2, int K2,
    const float* __restrict__ epi, u16* __restrict__ C, int N)
{
    __shared__ __align__(16) u16 lA[128 * 64];
    __shared__ __align__(16) u16 lB[128 * 64];

    const int tid  = threadIdx.x;
    const int bm   = blockIdx.y * 128;
    const int bn   = blockIdx.x * 128;
    const int wave = tid >> 6;
    const int lane = tid & 63;
    const int wr   = (wave >> 1) << 6;   // wave row offset within tile
    const int wc   = (wave & 1) << 6;    // wave col offset
    const int lrow = lane & 15;
    const int lkq  = lane >> 4;          // 0..3

    // staging: 256 threads, 4 calls each per matrix; lane-contiguous LDS dest
    const int sr = tid >> 3;             // 0..31  (row within 32-row group)
    const int sc = (tid & 7) << 3;       // element offset within 64-wide K row

    f32x4 acc[4][4] = {};

    #pragma unroll
    for (int pair = 0; pair < (PAIR2 ? 2 : 1); ++pair) {
        const u16* A = (PAIR2 && pair) ? A2 : A1;
        const u16* B = (PAIR2 && pair) ? B2 : B1;
        const int  K = (PAIR2 && pair) ? K2 : K1;
        const u16* gA = A + (size_t)(bm + sr) * K + sc;
        const u16* gB = B + (size_t)(bn + sr) * K + sc;
        u16* sA = lA + sr * 64 + sc;
        u16* sB = lB + sr * 64 + sc;
        const int nkt = K >> 6;
        for (int kt = 0; kt < nkt; ++kt) {
            __syncthreads();              // previous tile's reads done
            const u16* ga = gA + kt * 64;
            const u16* gb = gB + kt * 64;
            #pragma unroll
            for (int i = 0; i < 4; ++i)
                async_ld16(ga + (size_t)i * 32 * K, sA + i * 32 * 64);
            #pragma unroll
            for (int i = 0; i < 4; ++i)
                async_ld16(gb + (size_t)i * 32 * K, sB + i * 32 * 64);
            __syncthreads();              // drains vmcnt -> LDS writes visible
            #pragma unroll
            for (int ks = 0; ks < 2; ++ks) {
                bf16x8 af[4], bfr[4];
                #pragma unroll
                for (int i = 0; i < 4; ++i)
                    af[i] = *(const bf16x8*)(lA + (wr + i * 16 + lrow) * 64 + ks * 32 + lkq * 8);
                #pragma unroll
                for (int i = 0; i < 4; ++i)
                    bfr[i] = *(const bf16x8*)(lB + (wc + i * 16 + lrow) * 64 + ks * 32 + lkq * 8);
                #pragma unroll
                for (int mi = 0; mi < 4; ++mi)
                    #pragma unroll
                    for (int ni = 0; ni < 4; ++ni)
                        acc[mi][ni] = __builtin_amdgcn_mfma_f32_16x16x32_bf16(
                            af[mi], bfr[ni], acc[mi][ni], 0, 0, 0);
            }
        }
    }

    // epilogue: D row = (lane>>4)*4 + reg, col = lane&15  [m89/m91-verified]
    const int rbase = bm + wr + lkq * 4;
    const int cbase = bn + wc + lrow;
    if (BIAS_RELU) {
        #pragma unroll
        for (int ni = 0; ni < 4; ++ni) {
            const float bv = epi[cbase + ni * 16];
            #pragma unroll
            for (int mi = 0; mi < 4; ++mi)
                #pragma unroll
                for (int r = 0; r < 4; ++r) {
                    float v = acc[mi][ni][r] + bv;
                    v = fmaxf(v, 0.f);
                    C[(size_t)(rbase + mi * 16 + r) * N + cbase + ni * 16] = f2bf(v);
                }
        }
    } else {
        #pragma unroll
        for (int mi = 0; mi < 4; ++mi)
            #pragma unroll
            for (int r = 0; r < 4; ++r) {
                const float sv = epi[rbase + mi * 16 + r];
                #pragma unroll
                for (int ni = 0; ni < 4; ++ni)
                    C[(size_t)(rbase + mi * 16 + r) * N + cbase + ni * 16] =
                        f2bf(acc[mi][ni][r] * sv);
            }
    }
}

// ---------------- classifier GEMM (N=16) ----------------
__device__ __forceinline__ float bfdot2(u32 a, u32 b, float acc) {
    float al = __uint_as_float(a << 16), ah = __uint_as_float(a & 0xffff0000u);
    float bl = __uint_as_float(b << 16), bh = __uint_as_float(b & 0xffff0000u);
    return fmaf(ah, bh, fmaf(al, bl, acc));
}

__global__ __launch_bounds__(256) void gemm_cls(
    const u16* __restrict__ hc, const u16* __restrict__ Wc2,
    const float* __restrict__ bc2, float* __restrict__ out)
{
    const int c = threadIdx.x & 15;
    const int r = threadIdx.x >> 4;              // 16 rows per block
    const int row = blockIdx.x * 16 + r;
    const uint4* hp = (const uint4*)(hc + (size_t)row * NP);
    const uint4* wp = (const uint4*)(Wc2 + (size_t)c * NP);
    float acc = 0.f;
    #pragma unroll 4
    for (int i = 0; i < NP / 8; ++i) {
        uint4 a = hp[i], b = wp[i];
        acc = bfdot2(a.x, b.x, acc);
        acc = bfdot2(a.y, b.y, acc);
        acc = bfdot2(a.z, b.z, acc);
        acc = bfdot2(a.w, b.w, acc);
    }
    out[(size_t)row * 16 + c] = acc + bc2[c];
}

// ---------------- launch ----------------

extern "C" void kernel_launch(void* const* d_in, const int* in_sizes, int n_in,
                              void* d_out, int out_size, void* d_ws, size_t ws_size,
                              hipStream_t stream) {
    const float* gene  = (const float*)d_in[0];
    const float* train = (const float*)d_in[1];
    const int*   esrc  = (const int*)d_in[2];
    const int*   edst  = (const int*)d_in[3];
    const float* W1s   = (const float*)d_in[4];
    const float* W1n   = (const float*)d_in[5];
    const float* b1    = (const float*)d_in[6];
    const float* W2s   = (const float*)d_in[7];
    const float* W2n   = (const float*)d_in[8];
    const float* b2    = (const float*)d_in[9];
    const float* Wc1   = (const float*)d_in[10];
    const float* bc1   = (const float*)d_in[11];
    const float* Wc2   = (const float*)d_in[12];
    const float* bc2   = (const float*)d_in[13];
    const int E = in_sizes[2];

    char* ws = (char*)d_ws;
    // layout (all offsets multiple of 256)
    const size_t o_acnt  = 0;                       // fp32 counts [M,NP]  (later: h)
    const size_t o_acntb = 167772160;               // bf16 counts         (later: h2)
    const size_t o_mean  = 251658240;               // bf16 mean_src       (later: hc)
    const size_t o_train = 335544320;               // bf16 train [M,K1P]
    const size_t o_w1s   = 423624704;               // [NP,K1P]
    const size_t o_w1n   = 437387264;               // [NP,NP]
    const size_t o_w2s   = 450494464;
    const size_t o_w2n   = 463601664;
    const size_t o_wc1   = 476708864;
    const size_t o_gft   = 489816064;               // gene_feat^T bf16 [NP,NP]
    const size_t o_wc2   = 502923264;               // [16,NP]
    const size_t o_b1    = 503005184;
    const size_t o_b2    = 503015424;
    const size_t o_bc1   = 503025664;
    const size_t o_rdeg  = 503035904;
    // end ~503.1 MB

    float* ACNT = (float*)(ws + o_acnt);
    u16* ACNTB  = (u16*)(ws + o_acntb);
    u16* MEAN   = (u16*)(ws + o_mean);
    u16* TRAINB = (u16*)(ws + o_train);
    u16* W1S    = (u16*)(ws + o_w1s);
    u16* W1N    = (u16*)(ws + o_w1n);
    u16* W2S    = (u16*)(ws + o_w2s);
    u16* W2N    = (u16*)(ws + o_w2n);
    u16* WC1    = (u16*)(ws + o_wc1);
    u16* GFT    = (u16*)(ws + o_gft);
    u16* WC2    = (u16*)(ws + o_wc2);
    float* B1   = (float*)(ws + o_b1);
    float* B2   = (float*)(ws + o_b2);
    float* BC1  = (float*)(ws + o_bc1);
    float* RDEG = (float*)(ws + o_rdeg);
    u16* H  = (u16*)(ws + o_acnt);    // alias: counts fp32 dead after cvt+rdeg
    u16* H2 = (u16*)(ws + o_acntb);   // alias: counts bf16 dead after G1
    u16* HC = (u16*)(ws + o_mean);    // alias: mean dead after G3

    // 1. build dense counts + degree
    hipMemsetAsync(ACNT, 0, (size_t)MROWS * NP * 4, stream);
    build_counts<<<(E + 255) / 256, 256, 0, stream>>>(esrc, edst, E, ACNT);
    row_rdeg<<<MROWS, 64, 0, stream>>>(ACNT, RDEG);

    // 2. conversions / padding
    cvt_pad<<<MROWS, 256, 0, stream>>>(ACNT, ACNTB, MROWS, NP, NP);   // counts exact in bf16
    cvt_pad<<<MROWS, 256, 0, stream>>>(train, TRAINB, MROWS, 2675, K1P);
    cvt_pad<<<NP, 256, 0, stream>>>(W1s, W1S, 2500, 2675, K1P);
    cvt_pad<<<NP, 256, 0, stream>>>(W1n, W1N, 2500, 2500, NP);
    cvt_pad<<<NP, 256, 0, stream>>>(W2s, W2S, 2500, 2500, NP);
    cvt_pad<<<NP, 256, 0, stream>>>(W2n, W2N, 2500, 2500, NP);
    cvt_pad<<<NP, 256, 0, stream>>>(Wc1, WC1, 2500, 2500, NP);
    cvt_pad<<<16, 256, 0, stream>>>(Wc2, WC2, 16, 2500, NP);
    transpose_cvt<<<dim3(NP / 64, NP / 64), dim3(64, 4), 0, stream>>>(gene, GFT);
    pad_vec<<<(NP + 255) / 256, 256, 0, stream>>>(b1, B1, 2500, NP);
    pad_vec<<<(NP + 255) / 256, 256, 0, stream>>>(b2, B2, 2500, NP);
    pad_vec<<<(NP + 255) / 256, 256, 0, stream>>>(bc1, BC1, 2500, NP);

    const dim3 ggrid(NP / 128, MROWS / 128);
    // 3. G1: mean_src = (A @ gene_feat) * rdeg   [bf16 out]
    gemm_bt<false, false><<<ggrid, 256, 0, stream>>>(
        ACNTB, GFT, NP, nullptr, nullptr, 0, RDEG, MEAN, NP);
    // 4. G2: h = relu(train @ W1s^T + mean @ W1n^T + b1)
    gemm_bt<true, true><<<ggrid, 256, 0, stream>>>(
        TRAINB, W1S, K1P, MEAN, W1N, NP, B1, H, NP);
    // 5. G3: h2 = relu(h @ W2s^T + mean @ W2n^T + b2)
    gemm_bt<true, true><<<ggrid, 256, 0, stream>>>(
        H, W2S, NP, MEAN, W2N, NP, B2, H2, NP);
    // 6. G4: hc = relu(h2 @ Wc1^T + bc1)
    gemm_bt<false, true><<<ggrid, 256, 0, stream>>>(
        H2, WC1, NP, nullptr, nullptr, 0, BC1, HC, NP);
    // 7. G5: out = hc @ Wc2^T + bc2
    gemm_cls<<<MROWS / 16, 256, 0, stream>>>(HC, WC2, bc2, (float*)d_out);
}

// Round 2
// 2583.004 us; speedup vs baseline: 1.0741x; 1.0741x over previous
//
#include <hip/hip_runtime.h>
#include <stdint.h>

typedef unsigned short u16;
typedef unsigned int u32;
typedef __attribute__((ext_vector_type(4))) float f32x4;
typedef __attribute__((ext_vector_type(8))) short bf16x8;

#define MROWS 16384
#define NP    2560   // padded N / K for 2500-dims
#define K1P   2688   // padded K for 2675 (train_feat / W1_self)

// ---------------- helpers ----------------

__device__ __forceinline__ u16 f2bf(float f) {
    u32 u = __float_as_uint(f);
    u32 r = (u + 0x7fffu + ((u >> 16) & 1u)) >> 16;   // round-to-nearest-even
    return (u16)r;
}

__device__ __forceinline__ void async_ld16(const void* g, void* l) {
    __builtin_amdgcn_global_load_lds((const __attribute__((address_space(1))) u32*)g,
                                     (__attribute__((address_space(3))) u32*)l,
                                     16, 0, 0);
}

// ---------------- prep kernels ----------------

// fp32 [R,C] -> bf16 [gridDim.x, Cp], zero-padded. grid.x = Rp, block = 256.
__global__ void cvt_pad(const float* __restrict__ src, u16* __restrict__ dst,
                        int R, int C, int Cp) {
    const int r = blockIdx.x;
    u16* drow = dst + (size_t)r * Cp;
    if (r < R) {
        const float* srow = src + (size_t)r * C;
        for (int c = threadIdx.x; c < Cp; c += blockDim.x)
            drow[c] = (c < C) ? f2bf(srow[c]) : (u16)0;
    } else {
        for (int c = threadIdx.x; c < Cp; c += blockDim.x) drow[c] = 0;
    }
}

// fp32 vec [n] -> fp32 [np] zero-padded
__global__ void pad_vec(const float* __restrict__ src, float* __restrict__ dst,
                        int n, int np) {
    int i = blockIdx.x * blockDim.x + threadIdx.x;
    if (i < np) dst[i] = (i < n) ? src[i] : 0.f;
}

// gene_feat [2500,2500] fp32 -> dst [NP,NP] bf16, dst[n][k] = src[k][n], padded 0
__global__ void transpose_cvt(const float* __restrict__ src, u16* __restrict__ dst) {
    __shared__ float t[64][65];
    const int n0 = blockIdx.x * 64;
    const int k0 = blockIdx.y * 64;
    const int tx = threadIdx.x, ty = threadIdx.y;  // (64,4)
    for (int i = ty; i < 64; i += 4) {
        int k = k0 + i, n = n0 + tx;
        t[i][tx] = (k < 2500 && n < 2500) ? src[(size_t)k * 2500 + n] : 0.f;
    }
    __syncthreads();
    for (int i = ty; i < 64; i += 4)
        dst[(size_t)(n0 + i) * NP + k0 + tx] = f2bf(t[tx][i]);
}

__global__ void build_counts(const int* __restrict__ esrc, const int* __restrict__ edst,
                             int E, float* __restrict__ acnt) {
    int i = blockIdx.x * blockDim.x + threadIdx.x;
    if (i < E) atomicAdd(&acnt[(size_t)edst[i] * NP + esrc[i]], 1.0f);
}

// one wave per row: rdeg[row] = 1/max(rowsum,1)
__global__ void row_rdeg(const float* __restrict__ acnt, float* __restrict__ rdeg) {
    const int row = blockIdx.x;
    const float4* p = (const float4*)(acnt + (size_t)row * NP);
    float s = 0.f;
    for (int i = threadIdx.x; i < NP / 4; i += 64) {
        float4 v = p[i];
        s += v.x + v.y + v.z + v.w;
    }
    #pragma unroll
    for (int off = 32; off > 0; off >>= 1) s += __shfl_down(s, off, 64);
    if (threadIdx.x == 0) rdeg[row] = 1.f / fmaxf(s, 1.f);
}

// ---------------- main MFMA GEMM ----------------
// C[M,N](bf16) = epilogue( A1[M,K1] @ B1[N,K1]^T (+ A2[M,K2] @ B2[N,K2]^T) )
// BIAS_RELU: epilogue = relu(acc + bias[col]); else: acc * rdeg[row]
// All dims padded: M%128==0, N%128==0, K%64==0. All matrices bf16 row-major.
//
// LDS layout is XOR-swizzled to kill the 16-way bank conflict of the naive
// 128B-row layout: physical 16B chunk p of row r holds LOGICAL chunk p^(r&7).
// global_load_lds forces dst = wave-uniform base + lane*16, so the swizzle is
// applied on the GLOBAL SOURCE address (per-lane), not the LDS dest.
template<bool PAIR2, bool BIAS_RELU>
__global__ __launch_bounds__(256) void gemm_bt(
    const u16* __restrict__ A1, const u16* __restrict__ B1, int K1,
    const u16* __restrict__ A2, const u16* __restrict__ B2, int K2,
    const float* __restrict__ epi, u16* __restrict__ C, int N)
{
    __shared__ __align__(16) u16 lA[128 * 64];
    __shared__ __align__(16) u16 lB[128 * 64];

    const int tid  = threadIdx.x;
    const int bm   = blockIdx.y * 128;
    const int bn   = blockIdx.x * 128;
    const int wave = tid >> 6;
    const int lane = tid & 63;
    const int wr   = (wave >> 1) << 6;   // wave row offset within tile
    const int wc   = (wave & 1) << 6;    // wave col offset
    const int lrow = lane & 15;
    const int lkq  = lane >> 4;          // 0..3
    const int xr   = lrow & 7;           // fragment-read swizzle key

    // staging: 256 threads, 4 calls each per matrix; LDS dest lane-contiguous,
    // global source chunk XOR-swizzled so reads de-conflict.
    const int sr  = tid >> 3;                        // 0..31 (row in 32-row group)
    const int sc  = (tid & 7) << 3;                  // physical chunk offset (elems)
    const int gsw = (((tid & 7) ^ (sr & 7)) << 3);   // swizzled global chunk offset

    f32x4 acc[4][4] = {};

    #pragma unroll
    for (int pair = 0; pair < (PAIR2 ? 2 : 1); ++pair) {
        const u16* A = (PAIR2 && pair) ? A2 : A1;
        const u16* B = (PAIR2 && pair) ? B2 : B1;
        const int  K = (PAIR2 && pair) ? K2 : K1;
        const u16* gA = A + (size_t)(bm + sr) * K + gsw;
        const u16* gB = B + (size_t)(bn + sr) * K + gsw;
        u16* sA = lA + sr * 64 + sc;
        u16* sB = lB + sr * 64 + sc;
        const int nkt = K >> 6;
        for (int kt = 0; kt < nkt; ++kt) {
            __syncthreads();              // previous tile's reads done
            const u16* ga = gA + kt * 64;
            const u16* gb = gB + kt * 64;
            #pragma unroll
            for (int i = 0; i < 4; ++i)
                async_ld16(ga + (size_t)i * 32 * K, sA + i * 32 * 64);
            #pragma unroll
            for (int i = 0; i < 4; ++i)
                async_ld16(gb + (size_t)i * 32 * K, sB + i * 32 * 64);
            __syncthreads();              // drains vmcnt -> LDS writes visible
            #pragma unroll
            for (int ks = 0; ks < 2; ++ks) {
                bf16x8 af[4], bfr[4];
                #pragma unroll
                for (int i = 0; i < 4; ++i)
                    af[i] = *(const bf16x8*)(lA + (wr + i * 16 + lrow) * 64 +
                                             (((ks * 4 + lkq) ^ xr) << 3));
                #pragma unroll
                for (int i = 0; i < 4; ++i)
                    bfr[i] = *(const bf16x8*)(lB + (wc + i * 16 + lrow) * 64 +
                                              (((ks * 4 + lkq) ^ xr) << 3));
                #pragma unroll
                for (int mi = 0; mi < 4; ++mi)
                    #pragma unroll
                    for (int ni = 0; ni < 4; ++ni)
                        acc[mi][ni] = __builtin_amdgcn_mfma_f32_16x16x32_bf16(
                            af[mi], bfr[ni], acc[mi][ni], 0, 0, 0);
            }
        }
    }

    // epilogue: D row = (lane>>4)*4 + reg, col = lane&15  [m89/m91-verified]
    const int rbase = bm + wr + lkq * 4;
    const int cbase = bn + wc + lrow;
    if (BIAS_RELU) {
        #pragma unroll
        for (int ni = 0; ni < 4; ++ni) {
            const float bv = epi[cbase + ni * 16];
            #pragma unroll
            for (int mi = 0; mi < 4; ++mi)
                #pragma unroll
                for (int r = 0; r < 4; ++r) {
                    float v = acc[mi][ni][r] + bv;
                    v = fmaxf(v, 0.f);
                    C[(size_t)(rbase + mi * 16 + r) * N + cbase + ni * 16] = f2bf(v);
                }
        }
    } else {
        #pragma unroll
        for (int mi = 0; mi < 4; ++mi)
            #pragma unroll
            for (int r = 0; r < 4; ++r) {
                const float sv = epi[rbase + mi * 16 + r];
                #pragma unroll
                for (int ni = 0; ni < 4; ++ni)
                    C[(size_t)(rbase + mi * 16 + r) * N + cbase + ni * 16] =
                        f2bf(acc[mi][ni][r] * sv);
            }
    }
}

// ---------------- classifier GEMM (N=16) ----------------
__device__ __forceinline__ float bfdot2(u32 a, u32 b, float acc) {
    float al = __uint_as_float(a << 16), ah = __uint_as_float(a & 0xffff0000u);
    float bl = __uint_as_float(b << 16), bh = __uint_as_float(b & 0xffff0000u);
    return fmaf(ah, bh, fmaf(al, bl, acc));
}

__global__ __launch_bounds__(256) void gemm_cls(
    const u16* __restrict__ hc, const u16* __restrict__ Wc2,
    const float* __restrict__ bc2, float* __restrict__ out)
{
    const int c = threadIdx.x & 15;
    const int r = threadIdx.x >> 4;              // 16 rows per block
    const int row = blockIdx.x * 16 + r;
    const uint4* hp = (const uint4*)(hc + (size_t)row * NP);
    const uint4* wp = (const uint4*)(Wc2 + (size_t)c * NP);
    float acc = 0.f;
    #pragma unroll 4
    for (int i = 0; i < NP / 8; ++i) {
        uint4 a = hp[i], b = wp[i];
        acc = bfdot2(a.x, b.x, acc);
        acc = bfdot2(a.y, b.y, acc);
        acc = bfdot2(a.z, b.z, acc);
        acc = bfdot2(a.w, b.w, acc);
    }
    out[(size_t)row * 16 + c] = acc + bc2[c];
}

// ---------------- launch ----------------

extern "C" void kernel_launch(void* const* d_in, const int* in_sizes, int n_in,
                              void* d_out, int out_size, void* d_ws, size_t ws_size,
                              hipStream_t stream) {
    const float* gene  = (const float*)d_in[0];
    const float* train = (const float*)d_in[1];
    const int*   esrc  = (const int*)d_in[2];
    const int*   edst  = (const int*)d_in[3];
    const float* W1s   = (const float*)d_in[4];
    const float* W1n   = (const float*)d_in[5];
    const float* b1    = (const float*)d_in[6];
    const float* W2s   = (const float*)d_in[7];
    const float* W2n   = (const float*)d_in[8];
    const float* b2    = (const float*)d_in[9];
    const float* Wc1   = (const float*)d_in[10];
    const float* bc1   = (const float*)d_in[11];
    const float* Wc2   = (const float*)d_in[12];
    const float* bc2   = (const float*)d_in[13];
    const int E = in_sizes[2];

    char* ws = (char*)d_ws;
    // layout (all offsets multiple of 256)
    const size_t o_acnt  = 0;                       // fp32 counts [M,NP]  (later: h)
    const size_t o_acntb = 167772160;               // bf16 counts         (later: h2)
    const size_t o_mean  = 251658240;               // bf16 mean_src       (later: hc)
    const size_t o_train = 335544320;               // bf16 train [M,K1P]
    const size_t o_w1s   = 423624704;               // [NP,K1P]
    const size_t o_w1n   = 437387264;               // [NP,NP]
    const size_t o_w2s   = 450494464;
    const size_t o_w2n   = 463601664;
    const size_t o_wc1   = 476708864;
    const size_t o_gft   = 489816064;               // gene_feat^T bf16 [NP,NP]
    const size_t o_wc2   = 502923264;               // [16,NP]
    const size_t o_b1    = 503005184;
    const size_t o_b2    = 503015424;
    const size_t o_bc1   = 503025664;
    const size_t o_rdeg  = 503035904;
    // end ~503.1 MB

    float* ACNT = (float*)(ws + o_acnt);
    u16* ACNTB  = (u16*)(ws + o_acntb);
    u16* MEAN   = (u16*)(ws + o_mean);
    u16* TRAINB = (u16*)(ws + o_train);
    u16* W1S    = (u16*)(ws + o_w1s);
    u16* W1N    = (u16*)(ws + o_w1n);
    u16* W2S    = (u16*)(ws + o_w2s);
    u16* W2N    = (u16*)(ws + o_w2n);
    u16* WC1    = (u16*)(ws + o_wc1);
    u16* GFT    = (u16*)(ws + o_gft);
    u16* WC2    = (u16*)(ws + o_wc2);
    float* B1   = (float*)(ws + o_b1);
    float* B2   = (float*)(ws + o_b2);
    float* BC1  = (float*)(ws + o_bc1);
    float* RDEG = (float*)(ws + o_rdeg);
    u16* H  = (u16*)(ws + o_acnt);    // alias: counts fp32 dead after cvt+rdeg
    u16* H2 = (u16*)(ws + o_acntb);   // alias: counts bf16 dead after G1
    u16* HC = (u16*)(ws + o_mean);    // alias: mean dead after G3

    // 1. build dense counts + degree
    hipMemsetAsync(ACNT, 0, (size_t)MROWS * NP * 4, stream);
    build_counts<<<(E + 255) / 256, 256, 0, stream>>>(esrc, edst, E, ACNT);
    row_rdeg<<<MROWS, 64, 0, stream>>>(ACNT, RDEG);

    // 2. conversions / padding
    cvt_pad<<<MROWS, 256, 0, stream>>>(ACNT, ACNTB, MROWS, NP, NP);   // counts exact in bf16
    cvt_pad<<<MROWS, 256, 0, stream>>>(train, TRAINB, MROWS, 2675, K1P);
    cvt_pad<<<NP, 256, 0, stream>>>(W1s, W1S, 2500, 2675, K1P);
    cvt_pad<<<NP, 256, 0, stream>>>(W1n, W1N, 2500, 2500, NP);
    cvt_pad<<<NP, 256, 0, stream>>>(W2s, W2S, 2500, 2500, NP);
    cvt_pad<<<NP, 256, 0, stream>>>(W2n, W2N, 2500, 2500, NP);
    cvt_pad<<<NP, 256, 0, stream>>>(Wc1, WC1, 2500, 2500, NP);
    cvt_pad<<<16, 256, 0, stream>>>(Wc2, WC2, 16, 2500, NP);
    transpose_cvt<<<dim3(NP / 64, NP / 64), dim3(64, 4), 0, stream>>>(gene, GFT);
    pad_vec<<<(NP + 255) / 256, 256, 0, stream>>>(b1, B1, 2500, NP);
    pad_vec<<<(NP + 255) / 256, 256, 0, stream>>>(b2, B2, 2500, NP);
    pad_vec<<<(NP + 255) / 256, 256, 0, stream>>>(bc1, BC1, 2500, NP);

    const dim3 ggrid(NP / 128, MROWS / 128);
    // 3. G1: mean_src = (A @ gene_feat) * rdeg   [bf16 out]
    gemm_bt<false, false><<<ggrid, 256, 0, stream>>>(
        ACNTB, GFT, NP, nullptr, nullptr, 0, RDEG, MEAN, NP);
    // 4. G2: h = relu(train @ W1s^T + mean @ W1n^T + b1)
    gemm_bt<true, true><<<ggrid, 256, 0, stream>>>(
        TRAINB, W1S, K1P, MEAN, W1N, NP, B1, H, NP);
    // 5. G3: h2 = relu(h @ W2s^T + mean @ W2n^T + b2)
    gemm_bt<true, true><<<ggrid, 256, 0, stream>>>(
        H, W2S, NP, MEAN, W2N, NP, B2, H2, NP);
    // 6. G4: hc = relu(h2 @ Wc1^T + bc1)
    gemm_bt<false, true><<<ggrid, 256, 0, stream>>>(
        H2, WC1, NP, nullptr, nullptr, 0, BC1, HC, NP);
    // 7. G5: out = hc @ Wc2^T + bc2
    gemm_cls<<<MROWS / 16, 256, 0, stream>>>(HC, WC2, bc2, (float*)d_out);
}